// Round 5
// baseline (73.624 us; speedup 1.0000x reference)
//
#include <hip/hip_runtime.h>
#include <cstdint>
#include <cstddef>

#define B_  16
#define L_  8192
#define D_  256
#define NB_ 8
#define NW_ 128   // 64-token windows per batch row

// ws offsets in 4-byte units
static const long OFF_QK   = 0;        // 2048 floats
static const long OFF_QB   = 2048;     // 8 floats (pad to 4096)
static const long OFF_CNT  = 4096;     // 16384 ints  [b][n][w]
static const long OFF_OFFS = 20480;    // 16384 ints  exclusive scan
static const long OFF_TOT  = 36864;    // 128 ints    per (b,n) totals
static const long OFF_CIDX = 36992;    // <=131072 ints compacted token ids
static const long OFF_PART = 168064;   // part[NCH*128][2048] floats, then pse

// ---------------------------------------------------------------- k_setup
// 8 blocks, block h: qk[h][e] = (sum_d q[h*32+d] * Wk[256+h*32+d][e]) / sqrt(32).
__global__ __launch_bounds__(256) void k_setup(const float* __restrict__ query,
                                               const float* __restrict__ W,
                                               const float* __restrict__ bias,
                                               float* __restrict__ ws) {
    __shared__ float q_s[256];
    int t = threadIdx.x;
    int h = blockIdx.x;
    float acc = bias[t];
    const float* wr = W + (long)t * 256;
    #pragma unroll 8
    for (int e = 0; e < 256; e += 4) {
        float4 qv = *(const float4*)(query + e);
        float4 wv = *(const float4*)(wr + e);
        acc += qv.x * wv.x + qv.y * wv.y + qv.z * wv.z + qv.w * wv.w;
    }
    q_s[t] = acc;
    __syncthreads();
    const float rs = 0.17677669529663687f; // 1/sqrt(32)
    float s = 0.f;
    #pragma unroll 8
    for (int d = 0; d < 32; ++d) {
        int r = 256 + h * 32 + d;
        s += q_s[h * 32 + d] * W[(long)r * 256 + t];
    }
    ws[OFF_QK + h * 256 + t] = s * rs;
    if (t < 64) {
        float v = (t < 32) ? q_s[h * 32 + t] * bias[256 + h * 32 + t] : 0.f;
        v += __shfl_down(v, 16);
        v += __shfl_down(v, 8);
        v += __shfl_down(v, 4);
        v += __shfl_down(v, 2);
        v += __shfl_down(v, 1);
        if (t == 0) ws[OFF_QB + h] = v * rs;
    }
}

// ---------------------------------------------------------------- compaction
// Mask dtype detected at runtime: packed 0/1 bool bytes read as int32 give some
// word > 1 with probability 1-8^-64; a genuine int32 0/1 mask never does.
__global__ __launch_bounds__(256) void k_count(const unsigned char* __restrict__ mask,
                                               const int* __restrict__ bid,
                                               int* __restrict__ cnt) {
    int widx = threadIdx.x >> 6, lane = threadIdx.x & 63;
    int gw = blockIdx.x * 4 + widx;      // 2048 waves = 16 b * 128 w
    int b = gw >> 7, w = gw & 127;
    const int* mi = (const int*)mask;
    bool bytemode = __ballot((unsigned)mi[lane] > 1u) != 0ull;
    int tok = w * 64 + lane;
    long gl = (long)b * L_ + tok;
    bool valid = bytemode ? (mask[gl] != 0) : (mi[gl] != 0);
    int nl = valid ? bid[gl] : NB_;
    #pragma unroll
    for (int n = 0; n < NB_; ++n) {
        unsigned long long bn = __ballot(nl == n);
        if (lane == n) cnt[(b * NB_ + n) * NW_ + w] = __popcll(bn);
    }
}

__global__ __launch_bounds__(256) void k_scan(const int* __restrict__ cnt,
                                              int* __restrict__ offs,
                                              int* __restrict__ tot) {
    __shared__ int c[16384];
    __shared__ int sums[256];
    int t = threadIdx.x;
    for (int i = t; i < 16384; i += 256) c[i] = cnt[i];
    __syncthreads();
    int s = 0;
    int base0 = t * 64;
    for (int j = 0; j < 64; ++j) s += c[base0 + j];
    sums[t] = s;
    __syncthreads();
    for (int st = 1; st < 256; st <<= 1) {
        int v = (t >= st) ? sums[t - st] : 0;
        __syncthreads();
        sums[t] += v;
        __syncthreads();
    }
    int run = sums[t] - s; // exclusive base of this segment
    for (int j = 0; j < 64; ++j) {
        offs[base0 + j] = run;
        run += c[base0 + j];
    }
    // each (b,n) = 128 entries = segments 2t, 2t+1
    if (t < 128) {
        int hi = sums[2 * t + 1];
        int lo = (t > 0) ? sums[2 * t - 1] : 0;
        tot[t] = hi - lo;
    }
}

__global__ __launch_bounds__(256) void k_fill(const unsigned char* __restrict__ mask,
                                              const int* __restrict__ bid,
                                              const int* __restrict__ offs,
                                              int* __restrict__ cidx) {
    int widx = threadIdx.x >> 6, lane = threadIdx.x & 63;
    int gw = blockIdx.x * 4 + widx;
    int b = gw >> 7, w = gw & 127;
    const int* mi = (const int*)mask;
    bool bytemode = __ballot((unsigned)mi[lane] > 1u) != 0ull;
    int tok = w * 64 + lane;
    long gl = (long)b * L_ + tok;
    bool valid = bytemode ? (mask[gl] != 0) : (mi[gl] != 0);
    int nl = valid ? bid[gl] : NB_;
    unsigned long long ltmask = (1ull << lane) - 1ull; // lane=63 -> 0x7fff... correct
    #pragma unroll
    for (int n = 0; n < NB_; ++n) {
        unsigned long long bn = __ballot(nl == n);
        if (nl == n) {
            int ord = __popcll(bn & ltmask);
            cidx[offs[(b * NB_ + n) * NW_ + w] + ord] = tok;
        }
    }
}

// 3-step butterfly over low 3 lane bits: p0..p7 per-lane partials for h=0..7.
__device__ __forceinline__ float reduce_ep(float p0, float p1, float p2, float p3,
                                           float p4, float p5, float p6, float p7, int ep) {
    bool b1 = (ep & 1) != 0;
    float s0 = b1 ? p0 : p1, k0 = b1 ? p1 : p0;
    float s1 = b1 ? p2 : p3, k1 = b1 ? p3 : p2;
    float s2 = b1 ? p4 : p5, k2 = b1 ? p5 : p4;
    float s3 = b1 ? p6 : p7, k3 = b1 ? p7 : p6;
    float n0 = k0 + __shfl_xor(s0, 1);
    float n1 = k1 + __shfl_xor(s1, 1);
    float n2 = k2 + __shfl_xor(s2, 1);
    float n3 = k3 + __shfl_xor(s3, 1);
    bool b2 = (ep & 2) != 0;
    float t0s = b2 ? n0 : n1, t0k = b2 ? n1 : n0;
    float t1s = b2 ? n2 : n3, t1k = b2 ? n3 : n2;
    float m0 = t0k + __shfl_xor(t0s, 2);
    float m1 = t1k + __shfl_xor(t1s, 2);
    bool b4 = (ep & 4) != 0;
    float us = b4 ? m0 : m1, uk = b4 ? m1 : m0;
    return uk + __shfl_xor(us, 4);
}

// ---------------------------------------------------------------- k_gather
// Block = (b, n, chunk of the compacted list). Dense for-loop over indices:
// prefetchable, statically balanced, no divergence. Per pair: 2 coalesced 1KB
// row loads, in-register 8-head scores, butterfly reduce, exp, weighted acc.
template <int NCH>
__global__ __launch_bounds__(256) void k_gather(const float* __restrict__ x,
                                                const int* __restrict__ offs,
                                                const int* __restrict__ tot,
                                                const int* __restrict__ cidx,
                                                const float* __restrict__ ws,
                                                float* __restrict__ part,
                                                float* __restrict__ pse) {
    __shared__ float red[4 * 2048];
    __shared__ float rse[4 * 8];
    int t = threadIdx.x;
    int widx = t >> 6, lane = t & 63;
    int ep = lane & 7;

    int blk = blockIdx.x;
    int b = blk / (NB_ * NCH);
    int n = (blk / NCH) % NB_;
    int ch = blk % NCH;
    int bn = b * NB_ + n;
    int start = offs[bn * NW_];
    int cnt = tot[bn];
    int c0 = start + (int)((long)cnt * ch / NCH);
    int c1 = start + (int)((long)cnt * (ch + 1) / NCH);
    int len = c1 - c0;
    int w0 = c0 + (len * widx) / 4;
    int w1 = c0 + (len * (widx + 1)) / 4;

    const float* xb = x + (long)b * L_ * D_;

    float4 qk0 = *(const float4*)(ws + OFF_QK + 0 * 256 + lane * 4);
    float4 qk1 = *(const float4*)(ws + OFF_QK + 1 * 256 + lane * 4);
    float4 qk2 = *(const float4*)(ws + OFF_QK + 2 * 256 + lane * 4);
    float4 qk3 = *(const float4*)(ws + OFF_QK + 3 * 256 + lane * 4);
    float4 qk4 = *(const float4*)(ws + OFF_QK + 4 * 256 + lane * 4);
    float4 qk5 = *(const float4*)(ws + OFF_QK + 5 * 256 + lane * 4);
    float4 qk6 = *(const float4*)(ws + OFF_QK + 6 * 256 + lane * 4);
    float4 qk7 = *(const float4*)(ws + OFF_QK + 7 * 256 + lane * 4);
    float qbreg = ws[OFF_QB + ep];

    float4 acc[8];
    #pragma unroll
    for (int h = 0; h < 8; ++h) acc[h] = make_float4(0.f, 0.f, 0.f, 0.f);
    float se = 0.f;

    for (int i = w0; i < w1; i += 2) {
        int tokA = cidx[i];
        bool hasB = (i + 1) < w1;
        int tokB = cidx[hasB ? i + 1 : i];
        float gB = hasB ? 1.f : 0.f;
        float4 xa = ((const float4*)(xb + (long)tokA * D_))[lane];
        float4 xc = ((const float4*)(xb + (long)tokB * D_))[lane];
        float pA0 = xa.x*qk0.x + xa.y*qk0.y + xa.z*qk0.z + xa.w*qk0.w;
        float pA1 = xa.x*qk1.x + xa.y*qk1.y + xa.z*qk1.z + xa.w*qk1.w;
        float pA2 = xa.x*qk2.x + xa.y*qk2.y + xa.z*qk2.z + xa.w*qk2.w;
        float pA3 = xa.x*qk3.x + xa.y*qk3.y + xa.z*qk3.z + xa.w*qk3.w;
        float pA4 = xa.x*qk4.x + xa.y*qk4.y + xa.z*qk4.z + xa.w*qk4.w;
        float pA5 = xa.x*qk5.x + xa.y*qk5.y + xa.z*qk5.z + xa.w*qk5.w;
        float pA6 = xa.x*qk6.x + xa.y*qk6.y + xa.z*qk6.z + xa.w*qk6.w;
        float pA7 = xa.x*qk7.x + xa.y*qk7.y + xa.z*qk7.z + xa.w*qk7.w;
        float pB0 = xc.x*qk0.x + xc.y*qk0.y + xc.z*qk0.z + xc.w*qk0.w;
        float pB1 = xc.x*qk1.x + xc.y*qk1.y + xc.z*qk1.z + xc.w*qk1.w;
        float pB2 = xc.x*qk2.x + xc.y*qk2.y + xc.z*qk2.z + xc.w*qk2.w;
        float pB3 = xc.x*qk3.x + xc.y*qk3.y + xc.z*qk3.z + xc.w*qk3.w;
        float pB4 = xc.x*qk4.x + xc.y*qk4.y + xc.z*qk4.z + xc.w*qk4.w;
        float pB5 = xc.x*qk5.x + xc.y*qk5.y + xc.z*qk5.z + xc.w*qk5.w;
        float pB6 = xc.x*qk6.x + xc.y*qk6.y + xc.z*qk6.z + xc.w*qk6.w;
        float pB7 = xc.x*qk7.x + xc.y*qk7.y + xc.z*qk7.z + xc.w*qk7.w;
        float sA = reduce_ep(pA0, pA1, pA2, pA3, pA4, pA5, pA6, pA7, ep);
        float sB = reduce_ep(pB0, pB1, pB2, pB3, pB4, pB5, pB6, pB7, ep);
        sA += __shfl_xor(sA, 8);  sB += __shfl_xor(sB, 8);
        sA += __shfl_xor(sA, 16); sB += __shfl_xor(sB, 16);
        sA += __shfl_xor(sA, 32); sB += __shfl_xor(sB, 32);
        float wA = __expf(sA + qbreg);
        float wB = __expf(sB + qbreg) * gB;
        se += wA + wB;
        {
            float a = __shfl(wA, 0), c = __shfl(wB, 0);
            acc[0].x += a*xa.x + c*xc.x; acc[0].y += a*xa.y + c*xc.y;
            acc[0].z += a*xa.z + c*xc.z; acc[0].w += a*xa.w + c*xc.w;
        }
        {
            float a = __shfl(wA, 1), c = __shfl(wB, 1);
            acc[1].x += a*xa.x + c*xc.x; acc[1].y += a*xa.y + c*xc.y;
            acc[1].z += a*xa.z + c*xc.z; acc[1].w += a*xa.w + c*xc.w;
        }
        {
            float a = __shfl(wA, 2), c = __shfl(wB, 2);
            acc[2].x += a*xa.x + c*xc.x; acc[2].y += a*xa.y + c*xc.y;
            acc[2].z += a*xa.z + c*xc.z; acc[2].w += a*xa.w + c*xc.w;
        }
        {
            float a = __shfl(wA, 3), c = __shfl(wB, 3);
            acc[3].x += a*xa.x + c*xc.x; acc[3].y += a*xa.y + c*xc.y;
            acc[3].z += a*xa.z + c*xc.z; acc[3].w += a*xa.w + c*xc.w;
        }
        {
            float a = __shfl(wA, 4), c = __shfl(wB, 4);
            acc[4].x += a*xa.x + c*xc.x; acc[4].y += a*xa.y + c*xc.y;
            acc[4].z += a*xa.z + c*xc.z; acc[4].w += a*xa.w + c*xc.w;
        }
        {
            float a = __shfl(wA, 5), c = __shfl(wB, 5);
            acc[5].x += a*xa.x + c*xc.x; acc[5].y += a*xa.y + c*xc.y;
            acc[5].z += a*xa.z + c*xc.z; acc[5].w += a*xa.w + c*xc.w;
        }
        {
            float a = __shfl(wA, 6), c = __shfl(wB, 6);
            acc[6].x += a*xa.x + c*xc.x; acc[6].y += a*xa.y + c*xc.y;
            acc[6].z += a*xa.z + c*xc.z; acc[6].w += a*xa.w + c*xc.w;
        }
        {
            float a = __shfl(wA, 7), c = __shfl(wB, 7);
            acc[7].x += a*xa.x + c*xc.x; acc[7].y += a*xa.y + c*xc.y;
            acc[7].z += a*xa.z + c*xc.z; acc[7].w += a*xa.w + c*xc.w;
        }
    }

    #pragma unroll
    for (int h = 0; h < 8; ++h)
        *(float4*)(red + widx * 2048 + h * 256 + lane * 4) = acc[h];
    if (lane < 8) rse[widx * 8 + lane] = se;  // lane<8 => ep==lane
    __syncthreads();
    long base = (long)blk * 2048;
    for (int idx = t; idx < 2048; idx += 256) {
        float s = red[idx] + red[2048 + idx] + red[4096 + idx] + red[6144 + idx];
        part[base + idx] = s;
    }
    if (t < 8) pse[(long)blk * 8 + t] = rse[t] + rse[8 + t] + rse[16 + t] + rse[24 + t];
}

// ---------------------------------------------------------------- k_epi (unchanged)
template <int NCH>
__global__ __launch_bounds__(256) void k_epi(const float* __restrict__ part,
                                             const float* __restrict__ pse,
                                             const float* __restrict__ W,
                                             const float* __restrict__ ib,
                                             const float* __restrict__ Wo,
                                             const float* __restrict__ ob,
                                             const float* __restrict__ gamma,
                                             const float* __restrict__ beta,
                                             float* __restrict__ out) {
    __shared__ float pn[2048];
    __shared__ float ses[8];
    __shared__ float ctx_s[256];
    __shared__ float r1[4], r2[4];
    int n = blockIdx.x & 7, b = blockIdx.x >> 3;
    int t = threadIdx.x;
    int tbase = b * (NB_ * NCH) + n * NCH;
    if (t < 8) {
        float s = 0.f;
        for (int sub = 0; sub < NCH; ++sub) s += pse[(long)(tbase + sub) * 8 + t];
        ses[t] = s;
    }
    __syncthreads();
    bool has = ses[0] > 0.f;
    for (int j = 0; j < 8; ++j) {
        int idx = j * 256 + t;
        int h = idx >> 8;
        float s = 0.f;
        for (int sub = 0; sub < NCH; ++sub) s += part[(long)(tbase + sub) * 2048 + idx];
        pn[idx] = has ? s / ses[h] : 0.f;
    }
    __syncthreads();
    int h = t >> 5;
    float c = ib[512 + t];
    {
        const float* wr = W + (long)(512 + t) * 256;
        const float* ph = pn + h * 256;
        for (int e = 0; e < 256; e += 4) {
            float4 wv4 = *(const float4*)(wr + e);
            float4 pv4 = *(const float4*)(ph + e);
            c += wv4.x * pv4.x + wv4.y * pv4.y + wv4.z * pv4.z + wv4.w * pv4.w;
        }
    }
    ctx_s[t] = c;
    __syncthreads();
    float o = ob[t];
    {
        const float* wr = Wo + (long)t * 256;
        for (int d = 0; d < 256; d += 4) {
            float4 wv4 = *(const float4*)(wr + d);
            float4 cv4 = *(const float4*)(ctx_s + d);
            o += wv4.x * cv4.x + wv4.y * cv4.y + wv4.z * cv4.z + wv4.w * cv4.w;
        }
    }
    float s1 = o, s2 = o * o;
    #pragma unroll
    for (int off = 32; off >= 1; off >>= 1) {
        s1 += __shfl_down(s1, off);
        s2 += __shfl_down(s2, off);
    }
    if ((t & 63) == 0) { r1[t >> 6] = s1; r2[t >> 6] = s2; }
    __syncthreads();
    float S1 = r1[0] + r1[1] + r1[2] + r1[3];
    float S2 = r2[0] + r2[1] + r2[2] + r2[3];
    float mu = S1 * (1.f / 256.f);
    float var = S2 * (1.f / 256.f) - mu * mu;
    float rr = rsqrtf(var + 1e-5f);
    float res = ((o - mu) * rr * gamma[t] + beta[t]) * (has ? 1.f : 0.f);
    out[((long)b * 8 + n) * 256 + t] = res;
}

// ---------------------------------------------------------------- launch
extern "C" void kernel_launch(void* const* d_in, const int* in_sizes, int n_in,
                              void* d_out, int out_size, void* d_ws, size_t ws_size,
                              hipStream_t stream) {
    const float* x     = (const float*)d_in[0];
    const float* query = (const float*)d_in[1];
    const float* W     = (const float*)d_in[2];
    const float* ib    = (const float*)d_in[3];
    const float* Wo    = (const float*)d_in[4];
    const float* ob    = (const float*)d_in[5];
    const float* gamma = (const float*)d_in[6];
    const float* beta  = (const float*)d_in[7];
    const unsigned char* mask = (const unsigned char*)d_in[8];
    const int* bid     = (const int*)d_in[9];
    float* out = (float*)d_out;
    float* ws  = (float*)d_ws;
    int*   wsI = (int*)d_ws;

    k_setup<<<8, 256, 0, stream>>>(query, W, ib, ws);
    k_count<<<512, 256, 0, stream>>>(mask, bid, wsI + OFF_CNT);
    k_scan<<<1, 256, 0, stream>>>(wsI + OFF_CNT, wsI + OFF_OFFS, wsI + OFF_TOT);
    k_fill<<<512, 256, 0, stream>>>(mask, bid, wsI + OFF_OFFS, wsI + OFF_CIDX);

    auto need = [](long nch) {
        return (size_t)(OFF_PART + nch * 128L * 2048 + nch * 128L * 8) * 4;
    };
    float* part = ws + OFF_PART;
    if (ws_size >= need(8)) {
        const int NCH = 8; // 1024 blocks, 4096 waves
        float* pse = part + (long)NCH * 128 * 2048;
        k_gather<NCH><<<B_ * NB_ * NCH, 256, 0, stream>>>(
            x, wsI + OFF_OFFS, wsI + OFF_TOT, wsI + OFF_CIDX, ws, part, pse);
        k_epi<NCH><<<B_ * NB_, 256, 0, stream>>>(part, pse, W, ib, Wo, ob, gamma, beta, out);
    } else {
        const int NCH = 1;
        float* pse = part + (long)NCH * 128 * 2048;
        k_gather<NCH><<<B_ * NB_ * NCH, 256, 0, stream>>>(
            x, wsI + OFF_OFFS, wsI + OFF_TOT, wsI + OFF_CIDX, ws, part, pse);
        k_epi<NCH><<<B_ * NB_, 256, 0, stream>>>(part, pse, W, ib, Wo, ob, gamma, beta, out);
    }
}